// Round 4
// baseline (896.569 us; speedup 1.0000x reference)
//
#include <hip/hip_runtime.h>
#include <math.h>

#define N_TOKENS    16384
#define MODEL_DIM   2048
#define NUM_EXPERTS 64
#define NK          (N_TOKENS * 2)          // 32768

// d_out layout (float32 elements)
#define OFF_TOKEN_ORDER 0
#define OFF_REVERSED    (NK)                // 32768
#define OFF_COMBINE     (2 * NK)            // 65536
#define OFF_SPLITS      (3 * NK)            // 98304
#define OFF_PROBS       (3 * NK + NUM_EXPERTS)

#define BT 128           // tokens per gate block
#define BK 32            // k-tile
#define S_SPLITS 8       // k-splits
#define NSEG 256         // sort segments of 128 slots
#define LSTRIDE 65

typedef const __attribute__((address_space(1))) void g_void;
typedef __attribute__((address_space(3))) void l_void;

// ---------------------------------------------------------------------------
// Kernel 1: split-K gate partials. grid (128 tb, 8 sp) x 256.
// 8 tok x 4 exp per thread. Staging via global_load_lds width=16 with the
// bank swizzle (chunk' = (chunk + row/8) & 7) applied on the GLOBAL address
// side (LDS dst is lane-linear). fp32 chunk-32 accum, fp32 fold across tiles.
// ---------------------------------------------------------------------------
__global__ __launch_bounds__(256, 3) void gate_partial(
    const float* __restrict__ x,   // [N, D]
    const float* __restrict__ w,   // [E, D]
    float* __restrict__ partials,  // [128][8][128*64]
    int* __restrict__ ctrl)
{
    __shared__ __align__(16) float a_tile[BT * BK];           // 16 KB
    __shared__ __align__(16) float b_tile[NUM_EXPERTS * BK];  // 8 KB

    const int tid = threadIdx.x;
    const int tb = blockIdx.x;      // 0..127
    const int sp = blockIdx.y;      // 0..7
    if (tb == 0 && sp == 0 && tid == 0) { ctrl[0] = 0; ctrl[1] = 0; }

    const int t0 = tb * BT;
    const int kbase = sp * (MODEL_DIM / S_SPLITS);   // 256-k slice
    const int wv = tid >> 6, ln = tid & 63;
    const int tx = tid & 15;        // expert group (4 experts)
    const int ty = tid >> 4;        // token group  (8 tokens)

    // precompute lane->global row/chunk for swizzled staging
    int a_row[4], a_ch[4], b_row[2], b_ch[2];
#pragma unroll
    for (int q = 0; q < 4; q++) {
        const int p = wv * 4096 + q * 1024 + ln * 16;   // byte offset in a_tile
        const int row = p >> 7;                          // /128B per row
        const int cp = (p >> 4) & 7;                     // physical chunk
        a_row[q] = row;
        a_ch[q] = (cp - (row >> 3)) & 7;                 // logical chunk
    }
#pragma unroll
    for (int q = 0; q < 2; q++) {
        const int p = wv * 2048 + q * 1024 + ln * 16;
        const int row = p >> 7;
        const int cp = (p >> 4) & 7;
        b_row[q] = row;
        b_ch[q] = (cp - (row >> 3)) & 7;
    }

    float fold[8][4];
#pragma unroll
    for (int i = 0; i < 8; i++)
#pragma unroll
        for (int j = 0; j < 4; j++) fold[i][j] = 0.0f;

    for (int tile = 0; tile < 8; tile++) {
        const int k0 = kbase + tile * BK;
#pragma unroll
        for (int q = 0; q < 4; q++)
            __builtin_amdgcn_global_load_lds(
                (g_void*)(x + (size_t)(t0 + a_row[q]) * MODEL_DIM + k0 + a_ch[q] * 4),
                (l_void*)((char*)a_tile + wv * 4096 + q * 1024), 16, 0, 0);
#pragma unroll
        for (int q = 0; q < 2; q++)
            __builtin_amdgcn_global_load_lds(
                (g_void*)(w + (size_t)b_row[q] * MODEL_DIM + k0 + b_ch[q] * 4),
                (l_void*)((char*)b_tile + wv * 2048 + q * 1024), 16, 0, 0);
        __syncthreads();

        float accf[8][4];
#pragma unroll
        for (int i = 0; i < 8; i++)
#pragma unroll
            for (int j = 0; j < 4; j++) accf[i][j] = 0.0f;

#pragma unroll
        for (int k4 = 0; k4 < 8; k4++) {
            const float* ap = a_tile + ty * 256 + ((k4 + ty) & 7) * 4;        // rows ty*8+i, row>>3==ty
            const float* bp = b_tile + tx * 128 + ((k4 + (tx >> 1)) & 7) * 4; // rows tx*4+j, row>>3==tx>>1
            const float4 b0 = *(const float4*)(bp);
            const float4 b1 = *(const float4*)(bp + 32);
            const float4 b2 = *(const float4*)(bp + 64);
            const float4 b3 = *(const float4*)(bp + 96);
#pragma unroll
            for (int i = 0; i < 8; i++) {
                const float4 a = *(const float4*)(ap + i * 32);
                accf[i][0] += a.x * b0.x + a.y * b0.y + a.z * b0.z + a.w * b0.w;
                accf[i][1] += a.x * b1.x + a.y * b1.y + a.z * b1.z + a.w * b1.w;
                accf[i][2] += a.x * b2.x + a.y * b2.y + a.z * b2.z + a.w * b2.w;
                accf[i][3] += a.x * b3.x + a.y * b3.y + a.z * b3.z + a.w * b3.w;
            }
        }
#pragma unroll
        for (int i = 0; i < 8; i++)
#pragma unroll
            for (int j = 0; j < 4; j++) fold[i][j] += accf[i][j];
        __syncthreads();
    }

    float* dst = partials + ((size_t)tb * S_SPLITS + sp) * (BT * 64);
#pragma unroll
    for (int i = 0; i < 8; i++) {
        float4 v;
        v.x = fold[i][0]; v.y = fold[i][1]; v.z = fold[i][2]; v.w = fold[i][3];
        *(float4*)(dst + (ty * 8 + i) * 64 + tx * 4) = v;
    }
}

// ---------------------------------------------------------------------------
// Kernel 2 (fused): reduce partials + softmax/top-2/combine/probs + segHist,
// last-block scan (device-scope handshake), then per-block stable scatter.
// grid 256 blocks x 256 threads (1 block/CU -> co-resident; spin is safe).
// ---------------------------------------------------------------------------
__global__ __launch_bounds__(256) void moe_post(
    const float* __restrict__ partials,
    float* __restrict__ out,
    int* __restrict__ segHist,   // [256][64]
    int* __restrict__ segOff,    // [256][64]
    int* __restrict__ ctrl)      // [0]=done counter, [1]=flag
{
    __shared__ int h[NSEG * NUM_EXPERTS];   // 64 KB (aliased as logits in phase 1)
    __shared__ float inv_lds[64];
    __shared__ int hist[NUM_EXPERTS];
    __shared__ int flat_e[128];
    __shared__ int cnt[NUM_EXPERTS];
    __shared__ int segOffL[NUM_EXPERTS];
    __shared__ int gtot[4 * NUM_EXPERTS];
    __shared__ int base[NUM_EXPERTS];
    __shared__ int islast;

    float* l_lds = (float*)h;               // [64][LSTRIDE]
    const int tid = threadIdx.x;
    const int tb = blockIdx.x;              // 0..255
    const int t0 = tb * 64;
    const int pb = tb >> 1, half = tb & 1;

    // ---- phase 1: fp64 reduce of 8 fp32 partial slices ----
#pragma unroll
    for (int v = 0; v < 4; v++) {
        const int q = tid + v * 256;        // float4 index 0..1023
        const int t = q >> 4;
        const int c = (q & 15) * 4;
        double a0 = 0.0, a1 = 0.0, a2 = 0.0, a3 = 0.0;
        for (int s = 0; s < S_SPLITS; s++) {
            const float4 p = *(const float4*)(partials +
                ((size_t)(pb * S_SPLITS + s)) * (BT * 64) + (half * 64 + t) * 64 + c);
            a0 += (double)p.x; a1 += (double)p.y; a2 += (double)p.z; a3 += (double)p.w;
        }
        float* row = l_lds + t * LSTRIDE + c;
        row[0] = (float)a0; row[1] = (float)a1; row[2] = (float)a2; row[3] = (float)a3;
    }
    if (tid < NUM_EXPERTS) hist[tid] = 0;
    __syncthreads();

    // ---- softmax + top-2 + combine (1 thread/token) ----
    if (tid < 64) {
        const int t = tid;
        float* row = l_lds + t * LSTRIDE;
        float m = -INFINITY;
#pragma unroll
        for (int e = 0; e < NUM_EXPERTS; e++) m = fmaxf(m, row[e]);
        float l1 = -INFINITY, l2 = -INFINITY;
        int i1 = 0, i2 = 0;
        double s = 0.0;
        for (int e = 0; e < NUM_EXPERTS; e++) {
            const float l = row[e];
            if (l > l1) { l2 = l1; i2 = i1; l1 = l; i1 = e; }
            else if (l > l2) { l2 = l; i2 = e; }
            const float ex = expf(l - m);
            s += (double)ex;
            row[e] = ex;
        }
        const float inv = (float)(1.0 / s);
        inv_lds[t] = inv;
        const float p1 = expf(l1 - m) * inv;
        const float p2 = expf(l2 - m) * inv;
        const float e2 = expf(p2 - p1);
        const float r = 1.0f / (1.0f + e2);
        const int gtok = t0 + t;
        out[OFF_COMBINE + 2 * gtok]     = r;
        out[OFF_COMBINE + 2 * gtok + 1] = e2 * r;
        flat_e[2 * t]     = i1;
        flat_e[2 * t + 1] = i2;
        atomicAdd(&hist[i1], 1);
        atomicAdd(&hist[i2], 1);
    }
    __syncthreads();

    // publish segment hist (agent scope: cross-XCD visible once completed)
    if (tid < NUM_EXPERTS)
        __hip_atomic_store(&segHist[tb * NUM_EXPERTS + tid], hist[tid],
                           __ATOMIC_RELAXED, __HIP_MEMORY_SCOPE_AGENT);

    // probs write (coalesced)
#pragma unroll
    for (int r4 = 0; r4 < 4; r4++) {
        const int f = r4 * 1024 + tid * 4;
        const int t = f >> 6;
        const int e = f & 63;
        const float inv = inv_lds[t];
        float4 v;
        v.x = l_lds[t * LSTRIDE + e + 0] * inv;
        v.y = l_lds[t * LSTRIDE + e + 1] * inv;
        v.z = l_lds[t * LSTRIDE + e + 2] * inv;
        v.w = l_lds[t * LSTRIDE + e + 3] * inv;
        *(float4*)(out + OFF_PROBS + (size_t)(t0 + t) * NUM_EXPERTS + e) = v;
    }
    __syncthreads();   // drains this block's stores (incl. agent segHist stores)

    if (tid == 0) {
        const int old = __hip_atomic_fetch_add(&ctrl[0], 1,
                            __ATOMIC_ACQ_REL, __HIP_MEMORY_SCOPE_AGENT);
        islast = (old == NSEG - 1);
    }
    __syncthreads();

    if (islast) {
        // ---- scan: segOff[s][e] = base[e] + prefix_{s'<s} hist[s'][e] ----
        for (int i = tid; i < NSEG * NUM_EXPERTS; i += 256)
            h[i] = __hip_atomic_load(&segHist[i], __ATOMIC_RELAXED, __HIP_MEMORY_SCOPE_AGENT);
        __syncthreads();
        const int e = tid & 63;
        const int g = tid >> 6;
        int run = 0;
        for (int s = g * 64; s < g * 64 + 64; s++) {
            const int idx = s * NUM_EXPERTS + e;
            const int v = h[idx];
            h[idx] = run;
            run += v;
        }
        gtot[g * NUM_EXPERTS + e] = run;
        __syncthreads();
        if (tid < NUM_EXPERTS) {
            int b = 0;
#pragma unroll
            for (int gg = 0; gg < 4; gg++) {
                const int t = gtot[gg * NUM_EXPERTS + tid];
                gtot[gg * NUM_EXPERTS + tid] = b;
                b += t;
            }
            out[OFF_SPLITS + tid] = (float)b;
            int xs = b;
#pragma unroll
            for (int off = 1; off < 64; off <<= 1) {
                const int v = __shfl_up(xs, off);
                if (tid >= off) xs += v;
            }
            base[tid] = xs - b;
        }
        __syncthreads();
        const int myoff = gtot[g * NUM_EXPERTS + e] + base[e];
        for (int s = g * 64; s < g * 64 + 64; s++) {
            const int idx = s * NUM_EXPERTS + e;
            __hip_atomic_store(&segOff[idx], h[idx] + myoff,
                               __ATOMIC_RELAXED, __HIP_MEMORY_SCOPE_AGENT);
        }
        __syncthreads();   // drain agent stores
        if (tid == 0)
            __hip_atomic_store(&ctrl[1], 1, __ATOMIC_RELEASE, __HIP_MEMORY_SCOPE_AGENT);
    } else {
        if (tid == 0)
            while (__hip_atomic_load(&ctrl[1], __ATOMIC_ACQUIRE, __HIP_MEMORY_SCOPE_AGENT) == 0)
                __builtin_amdgcn_s_sleep(2);
        __syncthreads();
    }

    // ---- scatter this block's 128 slots (stable counting-sort placement) ----
    if (tid < NUM_EXPERTS) {
        segOffL[tid] = __hip_atomic_load(&segOff[tb * NUM_EXPERTS + tid],
                                         __ATOMIC_RELAXED, __HIP_MEMORY_SCOPE_AGENT);
        cnt[tid] = 0;
    }
    __syncthreads();

    int e = 0, rank = 0, pos = 0;
    unsigned long long match = 0;
    const int lane = tid & 63;
    const int wvv = tid >> 6;
    if (tid < 128) {
        e = flat_e[tid];
        match = ~0ull;
#pragma unroll
        for (int b = 0; b < 6; b++) {
            const unsigned long long m = __ballot((e >> b) & 1);
            match &= ((e >> b) & 1) ? m : ~m;
        }
        rank = __popcll(match & ((1ull << lane) - 1ull));
        if (wvv == 0) {
            pos = segOffL[e] + rank;
            if (lane == __builtin_ctzll(match)) cnt[e] = __popcll(match);
        }
    }
    __syncthreads();
    if (tid < 128) {
        if (wvv == 1) pos = segOffL[e] + cnt[e] + rank;
        const int ig = tb * 128 + tid;
        out[OFF_TOKEN_ORDER + pos] = (float)(ig >> 1);
        out[OFF_REVERSED + ig]     = (float)pos;
    }
}

// ---------------------------------------------------------------------------
extern "C" void kernel_launch(void* const* d_in, const int* in_sizes, int n_in,
                              void* d_out, int out_size, void* d_ws, size_t ws_size,
                              hipStream_t stream) {
    const float* x = (const float*)d_in[0];   // [16384, 2048] fp32
    const float* w = (const float*)d_in[1];   // [64, 2048] fp32
    float* out = (float*)d_out;

    int* ctrl    = (int*)d_ws;                            // 2 ints (+pad to 16B)
    int* segHist = ctrl + 4;                              // 256*64
    int* segOff  = segHist + NSEG * NUM_EXPERTS;          // 256*64
    float* partials = (float*)(segOff + NSEG * NUM_EXPERTS);  // 128*8*8192 fp32

    gate_partial<<<dim3(BT == 128 ? N_TOKENS / BT : 0, S_SPLITS), 256, 0, stream>>>(
        x, w, partials, ctrl);
    moe_post<<<NSEG, 256, 0, stream>>>(partials, out, segHist, segOff, ctrl);
}